// Round 7
// baseline (634.639 us; speedup 1.0000x reference)
//
#include <hip/hip_runtime.h>
#include <hip/hip_bf16.h>

// Problem constants (fixed by reference): B=4, L=4096, R=8, DV=64
#define BB  4
#define LL  4096
#define RR  8
#define DVV 64

typedef __bf16 bf16x8 __attribute__((ext_vector_type(8)));
typedef __bf16 bf16x4 __attribute__((ext_vector_type(4)));
typedef float  f32x4  __attribute__((ext_vector_type(4)));
typedef int    i32x4  __attribute__((ext_vector_type(4)));

#define LGKM_BARRIER() \
  asm volatile("s_waitcnt lgkmcnt(0)\n\ts_barrier" ::: "memory")

// ---------------------------------------------------------------------------
// Pre-kernel (256 blocks x 256 thr): v[b][m][d] fp32 -> vF fragment-linear
// bf16 MFMA B-fragments (unit = (b, colblk32, dblk16); lane l holds
// V[colblk*32 + (l>>4)*8 + j][dblk*16 + (l&15)], 16B contiguous per lane).
// ---------------------------------------------------------------------------
__global__ __launch_bounds__(256) void prep_kernel(
    const float* __restrict__ v, __bf16* __restrict__ vF) {
  __shared__ __bf16 tl[64][72];
  const int blk = blockIdx.x;         // 256 blocks
  const int b   = blk >> 6;           // 64 tiles per batch
  const int m0  = (blk & 63) << 6;
  const int tid = threadIdx.x;

  const float* vb = v + (((size_t)(b * LL + m0)) << 6);
#pragma unroll
  for (int i = 0; i < 16; ++i) {
    const int idx = (i << 8) + tid;   // m = idx>>6, d = idx&63
    tl[idx & 63][idx >> 6] = (__bf16)vb[idx];
  }
  __syncthreads();

  const int wv = tid >> 6, ln = tid & 63;
#pragma unroll
  for (int i = 0; i < 2; ++i) {
    const int u  = wv + (i << 2);
    const int cb = u >> 2, gg = u & 3;
    const int d  = gg * 16 + (ln & 15);
    const int c  = cb * 32 + ((ln >> 4) << 3);
    const size_t unit = ((size_t)(b * 128 + (m0 >> 5) + cb) << 2) + gg;
    *(bf16x8*)(vF + (unit << 9) + (ln << 3)) = *(const bf16x8*)&tl[d][c];
  }
}

// ---------------------------------------------------------------------------
// Main kernel: 512 WGs x 640 thr (10 waves: 8 COMPUTE + 2 STORE), 72.5 KB
// LDS -> 2 WGs/CU, whole grid resident. WG owns (b, 4 blocks of 8 rows).
//
// WHY wave specialization: vmcnt is a per-wave ORDERED FIFO over loads AND
// stores. Rounds 3/4/6 interleaved attn stores with PV's vF loads in the
// same wave -> every MFMA's s_waitcnt vmcnt(N) for its loads also forced
// all older stores to drain -> PV ran at store-drain rate with the store
// queue EMPTY during score (identical ~317us totals for 3 store shapes).
// Now: compute waves (0-7) do score+PV+O and NEVER store attn (their vmcnt
// waits see only loads); store waves (8-9) read pbuf/red from LDS and
// stream 4 rows each as 64 consecutive plain 1KB stores per block -- no
// loads, nothing ever waits on their FIFO, the store queue stays fed
// throughout score AND PV. Score is split into two column-half passes
// (ra2 reloaded per half, L2-hot) to keep compute VGPRs ~75 < 102 cap
// (round-5 spill lesson). O-reduction: 2-step osum4 (8 KB) so pbuf stays
// intact for the store waves. All barriers lgkm-only.
// ---------------------------------------------------------------------------
__global__ __launch_bounds__(640, 5) void attn_main(
    const float* __restrict__ ra1, const float* __restrict__ ra2,
    const int* __restrict__ mask, const __bf16* __restrict__ vF,
    float* __restrict__ out, float* __restrict__ attn) {
  __shared__ __bf16 pbuf[8 * 8 * 512];    // 64 KB: [wave][row][col] bf16 e
  __shared__ float  osum4[4 * 8 * 64];    // 8 KB: 2-step O reduction
  __shared__ float  red[8][8];            // [row][wave] partial row sums

  const int wg   = blockIdx.x;            // 0..511
  const int b    = wg >> 7;               // 128 WGs per batch
  const int blk0 = (wg & 127) << 2;       // 4 consecutive 8-row blocks
  const int tid  = threadIdx.x;
  const int wave = tid >> 6;              // 0..9
  const int lane = tid & 63;
  const int cw   = wave & 7;              // compute-wave index
  const int W    = cw << 9;               // compute wave's 512-col chunk
  const int lrow = lane & 15, kg = lane >> 4;
  const int lr8  = lrow & 7;              // A rows 8-15 duplicate rows 0-7

  const float* r2 = ra2 + (size_t)b * (RR * LL) + W + (lane << 2);
  const int*   mp = mask + (size_t)b * LL + W + (lane << 2);   // [B][1][L]

  f32x4 mA = {0.f, 0.f, 0.f, 0.f}, mB = {0.f, 0.f, 0.f, 0.f};
  if (wave < 8) {
    const i32x4 mAv = *(const i32x4*)mp;
    const i32x4 mBv = *(const i32x4*)(mp + 256);
#pragma unroll
    for (int j = 0; j < 4; ++j) {
      mA[j] = mAv[j] ? 1.0f : 0.0f;
      mB[j] = mBv[j] ? 1.0f : 0.0f;
    }
  }
  const __bf16* vFb = vF + ((size_t)b << 18);
  char* const   pw  = (char*)pbuf + (cw << 13);   // compute wave's 8 KB slice

#pragma unroll 1
  for (int jj = 0; jj < 4; ++jj) {
    const int row0 = (blk0 + jj) << 3;

    if (wave < 8) {
      // ---- score phase, two column-half passes (low VGPR pressure) ----
      const float* a_base = ra1 + ((size_t)b * LL + row0) * RR;
      float part[8];
      {  // half A: cols W + lane*4
        f32x4 rr_[RR];
#pragma unroll
        for (int r = 0; r < RR; ++r) rr_[r] = *(const f32x4*)(r2 + r * LL);
#pragma unroll
        for (int i = 0; i < 8; ++i) {
          const float* ap = a_base + i * RR;   // wave-uniform -> SMEM
          f32x4 s = {0.f, 0.f, 0.f, 0.f};
#pragma unroll
          for (int r = 0; r < RR; ++r)
#pragma unroll
            for (int j = 0; j < 4; ++j) s[j] = fmaf(ap[r], rr_[r][j], s[j]);
          f32x4 e;
#pragma unroll
          for (int j = 0; j < 4; ++j) e[j] = __expf(s[j]) * mA[j];
          part[i] = (e[0] + e[1]) + (e[2] + e[3]);
          bf16x4 p;
#pragma unroll
          for (int j = 0; j < 4; ++j) p[j] = (__bf16)e[j];
          *(bf16x4*)(pw + (i << 10) + ((lane << 3) ^ (i << 4))) = p;
        }
      }
      {  // half B: cols W + 256 + lane*4
        f32x4 rr_[RR];
#pragma unroll
        for (int r = 0; r < RR; ++r)
          rr_[r] = *(const f32x4*)(r2 + r * LL + 256);
#pragma unroll
        for (int i = 0; i < 8; ++i) {
          const float* ap = a_base + i * RR;
          f32x4 s = {0.f, 0.f, 0.f, 0.f};
#pragma unroll
          for (int r = 0; r < RR; ++r)
#pragma unroll
            for (int j = 0; j < 4; ++j) s[j] = fmaf(ap[r], rr_[r][j], s[j]);
          f32x4 e;
#pragma unroll
          for (int j = 0; j < 4; ++j) e[j] = __expf(s[j]) * mB[j];
          part[i] += (e[0] + e[1]) + (e[2] + e[3]);
          bf16x4 p;
#pragma unroll
          for (int j = 0; j < 4; ++j) p[j] = (__bf16)e[j];
          *(bf16x4*)(pw + (i << 10) + (512 + ((lane << 3) ^ (i << 4)))) = p;
        }
      }
      // 8 independent butterfly chains, interleaved
#pragma unroll
      for (int s = 1; s < 64; s <<= 1)
#pragma unroll
        for (int i = 0; i < 8; ++i) part[i] += __shfl_xor(part[i], s);
      if (lane == 0) {
#pragma unroll
        for (int i = 0; i < 8; ++i) red[i][cw] = part[i];
      }
    }
    LGKM_BARRIER();   // A: pbuf + red ready

    f32x4 acc[4];
    if (wave < 8) {
      // ---- PV MFMA: LOADS ONLY, no stores in this wave's FIFO ----
#pragma unroll
      for (int g = 0; g < 4; ++g) acc[g] = (f32x4){0.f, 0.f, 0.f, 0.f};
#pragma unroll
      for (int t = 0; t < 16; ++t) {
        const bf16x8 af = *(const bf16x8*)(
            pw + (lr8 << 10) + (((t << 6) + (kg << 4)) ^ (lr8 << 4)));
        const __bf16* vblk =
            vFb + ((size_t)((cw << 4) + t) << 11) + (lane << 3);
#pragma unroll
        for (int g = 0; g < 4; ++g) {
          const bf16x8 bf = *(const bf16x8*)(vblk + (g << 9));
          acc[g] =
              __builtin_amdgcn_mfma_f32_16x16x32_bf16(af, bf, acc[g], 0, 0, 0);
        }
      }
      // osum stage 1: waves 4-7 write
      if (wave >= 4 && kg < 2) {
#pragma unroll
        for (int g = 0; g < 4; ++g)
#pragma unroll
          for (int ii = 0; ii < 4; ++ii)
            osum4[((wave - 4) * 8 + kg * 4 + ii) * 64 + g * 16 + lrow] =
                acc[g][ii];
      }
      LGKM_BARRIER();   // B
      // osum stage 2: waves 0-3 accumulate
      if (wave < 4 && kg < 2) {
#pragma unroll
        for (int g = 0; g < 4; ++g)
#pragma unroll
          for (int ii = 0; ii < 4; ++ii)
            osum4[(wave * 8 + kg * 4 + ii) * 64 + g * 16 + lrow] +=
                acc[g][ii];
      }
    } else {
      // ---- STORE waves: 4 rows each, 64 consecutive 1KB plain stores ----
      const int w2 = (wave - 8) << 2;   // first row: 0 or 4
#pragma unroll
      for (int rr2 = 0; rr2 < 4; ++rr2) {
        const int r = w2 + rr2;
        float rs = 0.f;
#pragma unroll
        for (int v2 = 0; v2 < 8; ++v2) rs += red[r][v2];
        const float rinv_r = 1.0f / rs;
        float* arow =
            attn + ((size_t)b * LL + row0 + r) * LL + (lane << 2);
#pragma unroll
        for (int t = 0; t < 16; ++t) {
          const bf16x4 q = *(const bf16x4*)(
              (const char*)pbuf + ((t >> 1) << 13) + (r << 10) +
              ((t & 1) << 9) + ((lane << 3) ^ (r << 4)));
          f32x4 o;
#pragma unroll
          for (int j = 0; j < 4; ++j) o[j] = (float)q[j] * rinv_r;
          *(f32x4*)(arow + (t << 8)) = o;   // fire-and-forget
        }
      }
      LGKM_BARRIER();   // B (store waves' arrival)
    }
    LGKM_BARRIER();     // C: osum4 stage-2 complete

    if (tid < 128) {
      const int orow = tid >> 4;          // 0..7
      const int d    = (tid & 15) << 2;   // 0,4,..,60
      f32x4 o = {0.f, 0.f, 0.f, 0.f};
#pragma unroll
      for (int w = 0; w < 4; ++w) {
        const f32x4 rr = *(const f32x4*)(osum4 + ((w * 8 + orow) << 6) + d);
#pragma unroll
        for (int j = 0; j < 4; ++j) o[j] += rr[j];
      }
      float rt = 0.f;
#pragma unroll
      for (int w = 0; w < 8; ++w) rt += red[orow][w];
      const float rinv_o = 1.0f / rt;   // deferred normalization of PV
#pragma unroll
      for (int j = 0; j < 4; ++j) o[j] *= rinv_o;
      *(f32x4*)(out + ((size_t)b * LL + row0 + orow) * DVV + d) = o;
    }
    LGKM_BARRIER();     // D: red/pbuf free for next block
  }
}

extern "C" void kernel_launch(void* const* d_in, const int* in_sizes, int n_in,
                              void* d_out, int out_size, void* d_ws,
                              size_t ws_size, hipStream_t stream) {
  (void)in_sizes; (void)n_in; (void)out_size; (void)ws_size;
  const float* v    = (const float*)d_in[0];
  const int*   mask = (const int*)d_in[1];
  const float* ra1  = (const float*)d_in[2];
  const float* ra2  = (const float*)d_in[3];
  // d_in[4] = len_q, always 4096 (shapes fixed) -> constants above

  float* out  = (float*)d_out;
  float* attn = out + (size_t)BB * LL * DVV;   // outputs concatenated

  __bf16* vF = (__bf16*)d_ws;                  // 2 MB fragment-linear V

  hipLaunchKernelGGL(prep_kernel, dim3(BB * (LL / 64)), dim3(256), 0, stream,
                     v, vF);
  hipLaunchKernelGGL(attn_main, dim3(512), dim3(640), 0, stream,
                     ra1, ra2, mask, vF, out, attn);
}

// Round 8
// 358.926 us; speedup vs baseline: 1.7682x; 1.7682x over previous
//
#include <hip/hip_runtime.h>
#include <hip/hip_bf16.h>

// Problem constants (fixed by reference): B=4, L=4096, R=8, DV=64
#define BB  4
#define LL  4096
#define RR  8
#define DVV 64

typedef __bf16 bf16x8 __attribute__((ext_vector_type(8)));
typedef __bf16 bf16x4 __attribute__((ext_vector_type(4)));
typedef float  f32x4  __attribute__((ext_vector_type(4)));
typedef int    i32x4  __attribute__((ext_vector_type(4)));

#define LGKM_BARRIER() \
  asm volatile("s_waitcnt lgkmcnt(0)\n\ts_barrier" ::: "memory")

// ---------------------------------------------------------------------------
// Pre-kernel (256 blocks x 256 thr): v[b][m][d] fp32 -> vF fragment-linear
// bf16 MFMA B-fragments (unit = (b, colblk32, dblk16); lane l holds
// V[colblk*32 + (l>>4)*8 + j][dblk*16 + (l&15)], 16B contiguous per lane).
// ---------------------------------------------------------------------------
__global__ __launch_bounds__(256) void prep_kernel(
    const float* __restrict__ v, __bf16* __restrict__ vF) {
  __shared__ __bf16 tl[64][72];
  const int blk = blockIdx.x;         // 256 blocks
  const int b   = blk >> 6;           // 64 tiles per batch
  const int m0  = (blk & 63) << 6;
  const int tid = threadIdx.x;

  const float* vb = v + (((size_t)(b * LL + m0)) << 6);
#pragma unroll
  for (int i = 0; i < 16; ++i) {
    const int idx = (i << 8) + tid;   // m = idx>>6, d = idx&63
    tl[idx & 63][idx >> 6] = (__bf16)vb[idx];
  }
  __syncthreads();

  const int wv = tid >> 6, ln = tid & 63;
#pragma unroll
  for (int i = 0; i < 2; ++i) {
    const int u  = wv + (i << 2);
    const int cb = u >> 2, gg = u & 3;
    const int d  = gg * 16 + (ln & 15);
    const int c  = cb * 32 + ((ln >> 4) << 3);
    const size_t unit = ((size_t)(b * 128 + (m0 >> 5) + cb) << 2) + gg;
    *(bf16x8*)(vF + (unit << 9) + (ln << 3)) = *(const bf16x8*)&tl[d][c];
  }
}

// ---------------------------------------------------------------------------
// Main kernel: 2048 WGs x 640 thr (10 waves: 8 COMPUTE + 2 STORE), FLAT
// (one 8-row block per WG -- round 5/7 lesson: next to a 268 MB streaming
// write, L2 cross-time reuse is impossible, so WGs must read-once-use-now).
// LDS 72.3 KB -> 2 WGs/CU.
//
// Mechanism under clean test (round-7 attempt was confounded by persistence):
// vmcnt is a per-wave ORDERED FIFO over loads AND stores. Rounds 3/4/6 put
// attn stores in the same wave as PV's vF loads -> every MFMA's
// s_waitcnt vmcnt(N) also forced older stores to retire at the HBM-throttled
// L2-accept rate -> ~2.2 TB/s plateau, identical for 3 store shapes.
// Here compute waves (0-7) NEVER store attn (their FIFO sees only loads);
// store waves (8-9) read pbuf/red via LDS (lgkmcnt, not vmcnt) and stream
// 4 rows each = 64 consecutive plain 1KB stores, fire-and-forget -- their
// FIFO holds only stores and is never waited on, so the store queue stays
// fed through score AND PV of both resident WGs.
// Score: two column-half passes (32 ra2 regs; intra-WG reload is L2-hot)
// to stay well under the 102-VGPR cap at 5 waves/SIMD. O-reduction: 2-step
// osum4 (pbuf must stay intact for store waves). Barriers lgkm-only; each
// wave passes exactly one B barrier inside its role branch.
// ---------------------------------------------------------------------------
__global__ __launch_bounds__(640, 5) void attn_main(
    const float* __restrict__ ra1, const float* __restrict__ ra2,
    const int* __restrict__ mask, const __bf16* __restrict__ vF,
    float* __restrict__ out, float* __restrict__ attn) {
  __shared__ __bf16 pbuf[8 * 8 * 512];    // 64 KB: [wave][row][col] bf16 e
  __shared__ float  osum4[4 * 8 * 64];    // 8 KB: 2-step O reduction
  __shared__ float  red[8][8];            // [row][wave] partial row sums

  const int wg   = blockIdx.x;            // 0..2047
  const int b    = wg >> 9;               // 512 WGs per batch
  const int row0 = (wg & 511) << 3;       // 8 rows per WG
  const int tid  = threadIdx.x;
  const int wave = tid >> 6;              // 0..9
  const int lane = tid & 63;
  const int cw   = wave & 7;              // compute-wave index
  const int W    = cw << 9;               // compute wave's 512-col chunk
  const int lrow = lane & 15, kg = lane >> 4;
  const int lr8  = lrow & 7;              // A rows 8-15 duplicate rows 0-7

  const float*  r2  = ra2 + (size_t)b * (RR * LL) + W + (lane << 2);
  const __bf16* vFb = vF + ((size_t)b << 18);
  char* const   pw  = (char*)pbuf + (cw << 13);   // compute wave's 8 KB slice

  if (wave < 8) {
    // ---- mask for this wave's columns ----
    const int* mp = mask + (size_t)b * LL + W + (lane << 2);   // [B][1][L]
    const i32x4 mAv = *(const i32x4*)mp;
    const i32x4 mBv = *(const i32x4*)(mp + 256);
    f32x4 mA, mB;
#pragma unroll
    for (int j = 0; j < 4; ++j) {
      mA[j] = mAv[j] ? 1.0f : 0.0f;
      mB[j] = mBv[j] ? 1.0f : 0.0f;
    }

    // ---- score phase, two column-half passes (low VGPR pressure) ----
    const float* a_base = ra1 + ((size_t)b * LL + row0) * RR;
    float part[8];
    {  // half A: cols W + lane*4
      f32x4 rr_[RR];
#pragma unroll
      for (int r = 0; r < RR; ++r) rr_[r] = *(const f32x4*)(r2 + r * LL);
#pragma unroll
      for (int i = 0; i < 8; ++i) {
        const float* ap = a_base + i * RR;   // wave-uniform -> scalar loads
        f32x4 s = {0.f, 0.f, 0.f, 0.f};
#pragma unroll
        for (int r = 0; r < RR; ++r)
#pragma unroll
          for (int j = 0; j < 4; ++j) s[j] = fmaf(ap[r], rr_[r][j], s[j]);
        f32x4 e;
#pragma unroll
        for (int j = 0; j < 4; ++j) e[j] = __expf(s[j]) * mA[j];
        part[i] = (e[0] + e[1]) + (e[2] + e[3]);
        bf16x4 p;
#pragma unroll
        for (int j = 0; j < 4; ++j) p[j] = (__bf16)e[j];
        *(bf16x4*)(pw + (i << 10) + ((lane << 3) ^ (i << 4))) = p;
      }
    }
    {  // half B: cols W + 256 + lane*4 (reload intra-WG, L2-hot)
      f32x4 rr_[RR];
#pragma unroll
      for (int r = 0; r < RR; ++r) rr_[r] = *(const f32x4*)(r2 + r * LL + 256);
#pragma unroll
      for (int i = 0; i < 8; ++i) {
        const float* ap = a_base + i * RR;
        f32x4 s = {0.f, 0.f, 0.f, 0.f};
#pragma unroll
        for (int r = 0; r < RR; ++r)
#pragma unroll
          for (int j = 0; j < 4; ++j) s[j] = fmaf(ap[r], rr_[r][j], s[j]);
        f32x4 e;
#pragma unroll
        for (int j = 0; j < 4; ++j) e[j] = __expf(s[j]) * mB[j];
        part[i] += (e[0] + e[1]) + (e[2] + e[3]);
        bf16x4 p;
#pragma unroll
        for (int j = 0; j < 4; ++j) p[j] = (__bf16)e[j];
        *(bf16x4*)(pw + (i << 10) + (512 + ((lane << 3) ^ (i << 4)))) = p;
      }
    }
    // 8 independent butterfly chains, interleaved -> latency pipelined
#pragma unroll
    for (int s = 1; s < 64; s <<= 1)
#pragma unroll
      for (int i = 0; i < 8; ++i) part[i] += __shfl_xor(part[i], s);
    if (lane == 0) {
#pragma unroll
      for (int i = 0; i < 8; ++i) red[i][cw] = part[i];
    }
  }
  LGKM_BARRIER();   // A: pbuf + red ready

  if (wave < 8) {
    // ---- PV MFMA: LOADS ONLY -- this wave's vmcnt FIFO has no stores ----
    f32x4 acc[4];
#pragma unroll
    for (int g = 0; g < 4; ++g) acc[g] = (f32x4){0.f, 0.f, 0.f, 0.f};
#pragma unroll
    for (int t = 0; t < 16; ++t) {
      const bf16x8 af = *(const bf16x8*)(
          pw + (lr8 << 10) + (((t << 6) + (kg << 4)) ^ (lr8 << 4)));
      const __bf16* vblk =
          vFb + ((size_t)((cw << 4) + t) << 11) + (lane << 3);
#pragma unroll
      for (int g = 0; g < 4; ++g) {
        const bf16x8 bf = *(const bf16x8*)(vblk + (g << 9));
        acc[g] =
            __builtin_amdgcn_mfma_f32_16x16x32_bf16(af, bf, acc[g], 0, 0, 0);
      }
    }
    // osum stage 1: waves 4-7 write. C/D: row=kg*4+ii (rows 0-7 -> kg<2)
    if (wave >= 4 && kg < 2) {
#pragma unroll
      for (int g = 0; g < 4; ++g)
#pragma unroll
        for (int ii = 0; ii < 4; ++ii)
          osum4[((wave - 4) * 8 + kg * 4 + ii) * 64 + g * 16 + lrow] =
              acc[g][ii];
    }
    LGKM_BARRIER();   // B (compute waves)
    // osum stage 2: waves 0-3 accumulate
    if (wave < 4 && kg < 2) {
#pragma unroll
      for (int g = 0; g < 4; ++g)
#pragma unroll
        for (int ii = 0; ii < 4; ++ii)
          osum4[(wave * 8 + kg * 4 + ii) * 64 + g * 16 + lrow] += acc[g][ii];
    }
  } else {
    // ---- STORE waves: 4 rows each, 64 consecutive plain 1KB stores.
    //      No global loads ever -> vmcnt FIFO never waited on. ----
    const int w2 = (wave - 8) << 2;   // first row: 0 or 4
#pragma unroll
    for (int rr2 = 0; rr2 < 4; ++rr2) {
      const int r = w2 + rr2;
      float rs = 0.f;
#pragma unroll
      for (int v2 = 0; v2 < 8; ++v2) rs += red[r][v2];
      const float rinv_r = 1.0f / rs;
      float* arow = attn + ((size_t)b * LL + row0 + r) * LL + (lane << 2);
#pragma unroll
      for (int t = 0; t < 16; ++t) {
        const bf16x4 q = *(const bf16x4*)(
            (const char*)pbuf + ((t >> 1) << 13) + (r << 10) +
            ((t & 1) << 9) + ((lane << 3) ^ (r << 4)));
        f32x4 o;
#pragma unroll
        for (int j = 0; j < 4; ++j) o[j] = (float)q[j] * rinv_r;
        *(f32x4*)(arow + (t << 8)) = o;   // fire-and-forget
      }
    }
    LGKM_BARRIER();   // B (store waves)
  }
  LGKM_BARRIER();     // C: osum4 stage-2 complete

  if (tid < 128) {
    const int orow = tid >> 4;          // 0..7
    const int d    = (tid & 15) << 2;   // 0,4,..,60
    f32x4 o = {0.f, 0.f, 0.f, 0.f};
#pragma unroll
    for (int w = 0; w < 4; ++w) {
      const f32x4 rr = *(const f32x4*)(osum4 + ((w * 8 + orow) << 6) + d);
#pragma unroll
      for (int j = 0; j < 4; ++j) o[j] += rr[j];
    }
    float rt = 0.f;
#pragma unroll
    for (int w = 0; w < 8; ++w) rt += red[orow][w];
    const float rinv_o = 1.0f / rt;   // deferred normalization of PV
#pragma unroll
    for (int j = 0; j < 4; ++j) o[j] *= rinv_o;
    *(f32x4*)(out + ((size_t)b * LL + row0 + orow) * DVV + d) = o;
  }
}

extern "C" void kernel_launch(void* const* d_in, const int* in_sizes, int n_in,
                              void* d_out, int out_size, void* d_ws,
                              size_t ws_size, hipStream_t stream) {
  (void)in_sizes; (void)n_in; (void)out_size; (void)ws_size;
  const float* v    = (const float*)d_in[0];
  const int*   mask = (const int*)d_in[1];
  const float* ra1  = (const float*)d_in[2];
  const float* ra2  = (const float*)d_in[3];
  // d_in[4] = len_q, always 4096 (shapes fixed) -> constants above

  float* out  = (float*)d_out;
  float* attn = out + (size_t)BB * LL * DVV;   // outputs concatenated

  __bf16* vF = (__bf16*)d_ws;                  // 2 MB fragment-linear V

  hipLaunchKernelGGL(prep_kernel, dim3(BB * (LL / 64)), dim3(256), 0, stream,
                     v, vF);
  hipLaunchKernelGGL(attn_main, dim3(BB * LL / 8), dim3(640), 0, stream,
                     ra1, ra2, mask, vF, out, attn);
}

// Round 9
// 318.876 us; speedup vs baseline: 1.9902x; 1.1256x over previous
//
#include <hip/hip_runtime.h>
#include <hip/hip_bf16.h>

// Problem constants (fixed by reference): B=4, L=4096, R=8, DV=64
#define BB  4
#define LL  4096
#define RR  8
#define DVV 64

typedef __bf16 bf16x8 __attribute__((ext_vector_type(8)));
typedef __bf16 bf16x4 __attribute__((ext_vector_type(4)));
typedef float  f32x4  __attribute__((ext_vector_type(4)));
typedef int    i32x4  __attribute__((ext_vector_type(4)));

#define LGKM_BARRIER() \
  asm volatile("s_waitcnt lgkmcnt(0)\n\ts_barrier" ::: "memory")

// ---------------------------------------------------------------------------
// Pre-kernel (256 blocks x 256 thr): v[b][m][d] fp32 -> vF fragment-linear
// bf16 MFMA B-fragments (unit = (b, colblk32, dblk16); lane l holds
// V[colblk*32 + (l>>4)*8 + j][dblk*16 + (l&15)], 16B contiguous per lane).
// ---------------------------------------------------------------------------
__global__ __launch_bounds__(256) void prep_kernel(
    const float* __restrict__ v, __bf16* __restrict__ vF) {
  __shared__ __bf16 tl[64][72];
  const int blk = blockIdx.x;         // 256 blocks
  const int b   = blk >> 6;           // 64 tiles per batch
  const int m0  = (blk & 63) << 6;
  const int tid = threadIdx.x;

  const float* vb = v + (((size_t)(b * LL + m0)) << 6);
#pragma unroll
  for (int i = 0; i < 16; ++i) {
    const int idx = (i << 8) + tid;   // m = idx>>6, d = idx&63
    tl[idx & 63][idx >> 6] = (__bf16)vb[idx];
  }
  __syncthreads();

  const int wv = tid >> 6, ln = tid & 63;
#pragma unroll
  for (int i = 0; i < 2; ++i) {
    const int u  = wv + (i << 2);
    const int cb = u >> 2, gg = u & 3;
    const int d  = gg * 16 + (ln & 15);
    const int c  = cb * 32 + ((ln >> 4) << 3);
    const size_t unit = ((size_t)(b * 128 + (m0 >> 5) + cb) << 2) + gg;
    *(bf16x8*)(vF + (unit << 9) + (ln << 3)) = *(const bf16x8*)&tl[d][c];
  }
}

// ---------------------------------------------------------------------------
// Main kernel: 2048 WGs x 512 thr (8 waves), 64.25 KB LDS -> 2 WGs/CU.
// == ROUND-6 KERNEL + ONE CHANGE: staggered store-chunk order. ==
//
// Diagnosis after rounds 3-8 (six null/negative structural levers: density,
// nt-flag, residency, trickling, stream linearity, wave specialization --
// all pinned at 1.4-2.7 TB/s effective write BW while fillBuffer does 6.2):
// every variant wrote row-parallel with 16 KB row stride and phase-lockstep
// chunk indices. HBM channels interleave on LOW address bits; row*16KB
// leaves them unchanged -> at any instant all concurrent stores target the
// same 1KB-column = same small channel subset (~1/8 of channels) -> ~2 TB/s.
// FIX: wave w of WG wg writes its row's 16 chunks in order
// tt = (t + 3*wg + 5*w) & 15. gcd(5,16)=1 -> the 8 waves cover 8 DISTINCT
// chunk-columns at every instant; WG offsets decorrelate the two resident
// WGs and the grid. Bytes, density, per-chunk linearity unchanged.
// ---------------------------------------------------------------------------
__global__ __launch_bounds__(512, 4) void attn_main(
    const float* __restrict__ ra1, const float* __restrict__ ra2,
    const int* __restrict__ mask, const __bf16* __restrict__ vF,
    float* __restrict__ out, float* __restrict__ attn) {
  __shared__ __bf16 pbuf[8 * 8 * 512];    // 64 KB: [wave][row][col] bf16 e
  __shared__ float  red[8][8];            // [row][wave] partial row sums

  const int wg   = blockIdx.x;            // 0..2047
  const int b    = wg >> 9;               // 512 WGs per batch
  const int row0 = (wg & 511) << 3;       // 8 rows per WG
  const int tid  = threadIdx.x;
  const int wave = tid >> 6;              // 0..7
  const int lane = tid & 63;
  const int W    = wave << 9;             // wave's 512-col compute chunk

  // ---- one-time: ra2 (8r x 2x4 cols) + mask into registers ----
  const float* r2 = ra2 + (size_t)b * (RR * LL) + W + (lane << 2);
  f32x4 rA[RR], rB[RR];
#pragma unroll
  for (int r = 0; r < RR; ++r) {
    rA[r] = *(const f32x4*)(r2 + r * LL);
    rB[r] = *(const f32x4*)(r2 + r * LL + 256);
  }
  const int* mp = mask + (size_t)b * LL + W + (lane << 2);   // mask [B][1][L]
  const i32x4 mAv = *(const i32x4*)mp;
  const i32x4 mBv = *(const i32x4*)(mp + 256);
  f32x4 mA, mB;
#pragma unroll
  for (int j = 0; j < 4; ++j) {
    mA[j] = mAv[j] ? 1.0f : 0.0f;
    mB[j] = mBv[j] ? 1.0f : 0.0f;
  }

  const float* a_base = ra1 + ((size_t)b * LL + row0) * RR;
  char* const  pw     = (char*)pbuf + (wave << 13);   // wave's 8 KB slice

  // ---- score phase: s -> e=exp(s)*mask, bf16 e -> LDS, per-row partials ----
  float part[8];
#pragma unroll
  for (int i = 0; i < 8; ++i) {
    const float* ap = a_base + i * RR;   // row-uniform -> scalar loads
    f32x4 sA = {0.f, 0.f, 0.f, 0.f}, sB = {0.f, 0.f, 0.f, 0.f};
#pragma unroll
    for (int r = 0; r < RR; ++r) {
      const float a = ap[r];
#pragma unroll
      for (int j = 0; j < 4; ++j) {
        sA[j] = fmaf(a, rA[r][j], sA[j]);
        sB[j] = fmaf(a, rB[r][j], sB[j]);
      }
    }
    f32x4 eA, eB;
#pragma unroll
    for (int j = 0; j < 4; ++j) {
      eA[j] = __expf(sA[j]) * mA[j];   // |s| <= ~17: exp safe in fp32
      eB[j] = __expf(sB[j]) * mB[j];
    }
    part[i] = ((eA[0] + eA[1]) + (eA[2] + eA[3])) +
              ((eB[0] + eB[1]) + (eB[2] + eB[3]));

    bf16x4 pA, pB;
#pragma unroll
    for (int j = 0; j < 4; ++j) { pA[j] = (__bf16)eA[j]; pB[j] = (__bf16)eB[j]; }
    // XOR swizzle (byte bits 4-6 ^ row): pure per-row permutation of 16B
    // blocks; matched by the PV b128 reads and store-chunk b64 reads.
    const int swz = (i & 7) << 4;
    *(bf16x4*)(pw + (i << 10) + (((lane << 3)) ^ swz))       = pA;
    *(bf16x4*)(pw + (i << 10) + ((512 + (lane << 3)) ^ swz)) = pB;
  }
  // 8 independent butterfly chains, interleaved -> latency pipelined
#pragma unroll
  for (int s = 1; s < 64; s <<= 1)
#pragma unroll
    for (int i = 0; i < 8; ++i) part[i] += __shfl_xor(part[i], s);
  if (lane == 0) {
#pragma unroll
    for (int i = 0; i < 8; ++i) red[i][wave] = part[i];
  }
  LGKM_BARRIER();   // pbuf + red complete (no global stores in flight yet)

  // ---- wave-uniform 1/rowsum for the row THIS wave will store ----
  float rs = 0.f;
#pragma unroll
  for (int v = 0; v < 8; ++v) rs += red[wave][v];
  const float rinv_w = 1.0f / rs;

  // ---- fused PV MFMA + staggered linear attn stores ----
  const int lrow = lane & 15, kg = lane >> 4;
  const int lr8  = lrow & 7;              // A rows 8-15 duplicate rows 0-7
  const int stag = (3 * wg + 5 * wave) & 15;   // channel-decorrelation offset
  f32x4 acc[4];
#pragma unroll
  for (int g = 0; g < 4; ++g) acc[g] = (f32x4){0.f, 0.f, 0.f, 0.f};
  const __bf16* vFb = vF + ((size_t)b << 18);
  // wave w stores row (row0+w), chunk order rotated by stag
  float* arow = attn + ((size_t)b * LL + row0 + wave) * LL;

#pragma unroll
  for (int t = 0; t < 16; ++t) {
    const bf16x8 af = *(const bf16x8*)(
        pw + (lr8 << 10) + (((t << 6) + (kg << 4)) ^ (lr8 << 4)));
    const __bf16* vblk =
        vFb + ((size_t)((wave << 4) + t) << 11) + (lane << 3);
#pragma unroll
    for (int g = 0; g < 4; ++g) {
      const bf16x8 bf = *(const bf16x8*)(vblk + (g << 9));
      acc[g] =
          __builtin_amdgcn_mfma_f32_16x16x32_bf16(af, bf, acc[g], 0, 0, 0);
    }
    // store chunk tt of row (row0+wave): cols [tt*256, tt*256+256).
    // tt walk is a bijection over 0..15; 8 waves are pairwise-distinct at
    // every instant (gcd(5,16)=1) -> stores spread across channel groups.
    const int tt = (t + stag) & 15;
    const bf16x4 q = *(const bf16x4*)(
        (const char*)pbuf + ((tt >> 1) << 13) + (wave << 10) +
        ((tt & 1) << 9) + ((lane << 3) ^ ((wave & 7) << 4)));
    f32x4 o;
#pragma unroll
    for (int j = 0; j < 4; ++j) o[j] = (float)q[j] * rinv_w;
    *(f32x4*)(arow + (tt << 8) + (lane << 2)) = o;
  }

  // ---- cross-wave O reduction: reuse pbuf (store-chunk LDS reads already
  //      retired into VGPRs); lgkm-only barriers keep global stores in
  //      flight ----
  LGKM_BARRIER();
  float* osum = (float*)pbuf;   // [8 waves][8 rows][64 d] fp32 = 16 KB
  // C/D layout: row = kg*4 + ii (valid rows 0-7 -> kg<2), col = g*16 + lrow
  if (kg < 2) {
#pragma unroll
    for (int g = 0; g < 4; ++g)
#pragma unroll
      for (int ii = 0; ii < 4; ++ii)
        osum[(wave * 8 + kg * 4 + ii) * 64 + g * 16 + lrow] = acc[g][ii];
  }
  LGKM_BARRIER();

  if (tid < 128) {
    const int orow = tid >> 4;          // 0..7
    const int d    = (tid & 15) << 2;   // 0,4,..,60
    f32x4 o = {0.f, 0.f, 0.f, 0.f};
#pragma unroll
    for (int w = 0; w < 8; ++w) {
      const f32x4 rr = *(const f32x4*)(osum + ((w * 8 + orow) << 6) + d);
#pragma unroll
      for (int j = 0; j < 4; ++j) o[j] += rr[j];
    }
    float rt = 0.f;
#pragma unroll
    for (int w = 0; w < 8; ++w) rt += red[orow][w];
    const float rinv_o = 1.0f / rt;   // deferred normalization of PV
#pragma unroll
    for (int j = 0; j < 4; ++j) o[j] *= rinv_o;
    *(f32x4*)(out + ((size_t)b * LL + row0 + orow) * DVV + d) = o;
  }
}

extern "C" void kernel_launch(void* const* d_in, const int* in_sizes, int n_in,
                              void* d_out, int out_size, void* d_ws,
                              size_t ws_size, hipStream_t stream) {
  (void)in_sizes; (void)n_in; (void)out_size; (void)ws_size;
  const float* v    = (const float*)d_in[0];
  const int*   mask = (const int*)d_in[1];
  const float* ra1  = (const float*)d_in[2];
  const float* ra2  = (const float*)d_in[3];
  // d_in[4] = len_q, always 4096 (shapes fixed) -> constants above

  float* out  = (float*)d_out;
  float* attn = out + (size_t)BB * LL * DVV;   // outputs concatenated

  __bf16* vF = (__bf16*)d_ws;                  // 2 MB fragment-linear V

  hipLaunchKernelGGL(prep_kernel, dim3(BB * (LL / 64)), dim3(256), 0, stream,
                     v, vF);
  hipLaunchKernelGGL(attn_main, dim3(BB * LL / 8), dim3(512), 0, stream,
                     ra1, ra2, mask, vF, out, attn);
}